// Round 1
// baseline (34.472 us; speedup 1.0000x reference)
//
#include <hip/hip_runtime.h>
#include <math.h>

#define BLOCK 256
#define TAPS 16
#define HALO (TAPS - 1)

__device__ __forceinline__ float eluf(float v) {
    return v > 0.0f ? v : expm1f(v);
}

// Compute (sr, si) for one batch element given xp = &x[b*128] viewed as float4.
__device__ __forceinline__ void compute_s(const float4* __restrict__ xp,
                                          const float* __restrict__ w1, float bias1,
                                          const float* __restrict__ w2,
                                          float b20, float b21,
                                          float& sr, float& si) {
    float h[4];
#pragma unroll
    for (int j = 0; j < 4; ++j) {
        float acc = bias1;
#pragma unroll
        for (int c = 0; c < 2; ++c) {
#pragma unroll
            for (int q = 0; q < 4; ++q) {
                float4 v = xp[c * 16 + j * 4 + q];
                const float* wp = w1 + c * 16 + q * 4;
                acc += v.x * wp[0] + v.y * wp[1] + v.z * wp[2] + v.w * wp[3];
            }
        }
        h[j] = eluf(acc);
    }
    float a0 = b20, a1 = b21;
#pragma unroll
    for (int j = 0; j < 4; ++j) {
        a0 += h[j] * w2[j];
        a1 += h[j] * w2[4 + j];
    }
    sr = eluf(a0);
    si = eluf(a1);
}

__global__ __launch_bounds__(BLOCK) void NF_20581483282566_kernel(
    const float* __restrict__ x,
    const float* __restrict__ w1, const float* __restrict__ b1,
    const float* __restrict__ w2, const float* __restrict__ b2,
    const float* __restrict__ tr, const float* __restrict__ ti,
    float* __restrict__ out, int B)
{
    __shared__ float s_r[BLOCK + HALO];
    __shared__ float s_i[BLOCK + HALO];

    const int t = threadIdx.x;
    const long b0 = (long)blockIdx.x * BLOCK;
    const long b = b0 + t;

    const float bias1 = b1[0];
    const float b20 = b2[0], b21 = b2[1];

    // Main element
    float sr = 0.f, si = 0.f;
    if (b < B) {
        compute_s(reinterpret_cast<const float4*>(x) + b * 32, w1, bias1, w2, b20, b21, sr, si);
    }
    s_r[HALO + t] = sr;
    s_i[HALO + t] = si;

    // Halo: recompute the previous block's last 15 elements (zeros before b=0,
    // matching the reference's zero-padding of the FIR input).
    if (t < HALO) {
        long hb = b0 - HALO + t;
        float hr = 0.f, hi = 0.f;
        if (hb >= 0) {
            compute_s(reinterpret_cast<const float4*>(x) + hb * 32, w1, bias1, w2, b20, b21, hr, hi);
        }
        s_r[t] = hr;
        s_i[t] = hi;
    }
    __syncthreads();

    if (b < B) {
        float yr = 0.f, yi = 0.f;
#pragma unroll
        for (int j = 0; j < TAPS; ++j) {
            float a  = s_r[HALO + t - j];
            float bb = s_i[HALO + t - j];
            float trj = tr[j], tij = ti[j];
            yr += a * trj - bb * tij;
            yi += a * tij + bb * trj;
        }
        reinterpret_cast<float2*>(out)[b] = make_float2(yr, yi);
    }
}

extern "C" void kernel_launch(void* const* d_in, const int* in_sizes, int n_in,
                              void* d_out, int out_size, void* d_ws, size_t ws_size,
                              hipStream_t stream) {
    const float* x  = (const float*)d_in[0];
    const float* w1 = (const float*)d_in[1];
    const float* b1 = (const float*)d_in[2];
    const float* w2 = (const float*)d_in[3];
    const float* b2 = (const float*)d_in[4];
    const float* tr = (const float*)d_in[5];
    const float* ti = (const float*)d_in[6];
    float* out = (float*)d_out;

    const int B = in_sizes[0] / 128;  // x is (B, 2, 64)
    const int grid = (B + BLOCK - 1) / BLOCK;
    NF_20581483282566_kernel<<<grid, BLOCK, 0, stream>>>(x, w1, b1, w2, b2, tr, ti, out, B);
}